// Round 3
// baseline (150.624 us; speedup 1.0000x reference)
//
#include <hip/hip_runtime.h>

#define B_ 64
#define S_ 512
#define H_ 768
#define L_ 9
#define TPB 16                       // tokens per block
#define BPR (S_ / TPB)               // 32 blocks per row

// ---------------------------------------------------------------------------
// Fused: per-row compaction + gathered GEMV (768->9) + softmax. f32 in/out.
// Block = 256 threads = 4 waves; wave w owns 4 output slots basep..basep+3.
//
// ROUND 3 — barrier-free load path. Previous structure serialized:
// mask->sync->srcrow scatter->sync->srcrow read->gather(900cy HBM)->compute,
// so the dominant loads issued ~1500cy into each block and barrier-convoyed
// (4 blocks/CU, in-phase). Now each WAVE scans the full row itself:
// 8 coalesced mask loads + 8 ballots -> row bitmap in wave-uniform u64s;
// slot->src = "select pp-th set bit", wave-uniform => pure SALU binary
// search (scalar pipe, free). Gathers issue BEFORE the single remaining
// barrier (W->LDS stage). No srcrow/wsum LDS, 3 syncs -> 1.
//
// Gather is coalesced: lane i loads float4 at rowbase+(j*64+i)*16, j=0..2;
// lane owns h in {256j+4i+k}. Cross-lane reduce makes GEMV invariant to the
// h->lane mapping; W->LDS transpose scatter matches.
// ---------------------------------------------------------------------------
__device__ __forceinline__ void bias_softmax(const float* __restrict__ bias,
                                             float* cprob) {
    float m = -3.4e38f;
#pragma unroll
    for (int c = 0; c < L_; c++) { cprob[c] = bias[c]; m = fmaxf(m, cprob[c]); }
    float s = 0.0f;
#pragma unroll
    for (int c = 0; c < L_; c++) { cprob[c] = __expf(cprob[c] - m); s += cprob[c]; }
    const float inv = 1.0f / s;
#pragma unroll
    for (int c = 0; c < L_; c++) cprob[c] *= inv;
}

__global__ __launch_bounds__(256) void ner_kernel(const float* __restrict__ seq,
                                                  const int* __restrict__ mask,
                                                  const float* __restrict__ W,
                                                  const float* __restrict__ bias,
                                                  float* __restrict__ out) {
    __shared__ float wt[L_ * 3 * 64 * 4];   // [(cls*3+j)*64+lane] float4s

    const int tid  = threadIdx.x;
    const int lane = tid & 63;
    // force wave-uniform values into SGPRs so slot->src select stays scalar
    const int w    = __builtin_amdgcn_readfirstlane(tid >> 6);
    const int row  = blockIdx.x & 63;        // sub-major swizzle
    const int sub  = blockIdx.x >> 6;

    // ---- per-wave full-row mask scan: 8 coalesced loads + 8 ballots ----
    const int* mrow = mask + row * S_;
    int mv[8];
#pragma unroll
    for (int k = 0; k < 8; k++) mv[k] = mrow[64 * k + lane];

    unsigned long long bm[8];
    int csum[9];
    csum[0] = 0;
#pragma unroll
    for (int k = 0; k < 8; k++) {
        bm[k] = __ballot(mv[k] != 0);
        csum[k + 1] = csum[k] + __popcll(bm[k]);
    }
    const int cnt = csum[8];

    // ---- whole-block early-out (uniform across waves: same cnt, same sub) ----
    if (sub * TPB >= cnt) {
        float cprob[L_];
        bias_softmax(bias, cprob);
        const int base = (row * S_ + sub * TPB) * L_;
        for (int idx = tid; idx < TPB * L_; idx += 256)
            out[base + idx] = cprob[idx % L_];
        return;
    }

    const int basep = sub * TPB + w * 4;

    // ---- slot->src via scalar bit-select, then issue gathers immediately ----
    float x[4][12];
#pragma unroll
    for (int t = 0; t < 4; t++) {
        const int pp = basep + t;
        if (pp < cnt) {                     // wave-uniform (scalar branch)
            // select pp-th set bit of the 512-bit row bitmap (all SALU)
            int k = 0;
#pragma unroll
            for (int j = 1; j < 8; j++) k += (pp >= csum[j]);
            int need = pp - csum[k];
            unsigned long long xm = bm[k];
            int src = 64 * k;
            int c32 = __popcll(xm & 0xFFFFFFFFull);
            if (need >= c32) { need -= c32; src += 32; xm >>= 32; }
            int c16 = __popcll(xm & 0xFFFFull);
            if (need >= c16) { need -= c16; src += 16; xm >>= 16; }
            int c8  = __popcll(xm & 0xFFull);
            if (need >= c8)  { need -= c8;  src += 8;  xm >>= 8; }
            int c4  = __popcll(xm & 0xFull);
            if (need >= c4)  { need -= c4;  src += 4;  xm >>= 4; }
            int c2  = __popcll(xm & 0x3ull);
            if (need >= c2)  { need -= c2;  src += 2;  xm >>= 2; }
            int c1  = (int)(xm & 1ull);
            if (need >= c1)  { src += 1; }

            const float4* p4 = reinterpret_cast<const float4*>(
                seq + ((size_t)row * S_ + src) * H_) + lane;
            float4 a0 = p4[0], a1 = p4[64], a2 = p4[128];
            x[t][0] = a0.x; x[t][1] = a0.y; x[t][2]  = a0.z; x[t][3]  = a0.w;
            x[t][4] = a1.x; x[t][5] = a1.y; x[t][6]  = a1.z; x[t][7]  = a1.w;
            x[t][8] = a2.x; x[t][9] = a2.y; x[t][10] = a2.z; x[t][11] = a2.w;
        } else {
#pragma unroll
            for (int kk = 0; kk < 12; kk++) x[t][kk] = 0.0f;  // -> softmax(bias)
        }
    }

    // ---- W -> LDS (coalesced global reads, transposed scatter into LDS) ----
    // Lane ln owns h = 256*j + 4*ln + k:  wt[((c*3+j)*64+ln)*4+k] = W[h*9+c]
    for (int idx = tid; idx < H_ * L_; idx += 256) {
        float val = W[idx];
        int h  = idx / 9;
        int c  = idx - 9 * h;
        int j  = h >> 8;
        int r  = h & 255;
        int ln = r >> 2;
        int k  = r & 3;
        wt[((c * 3 + j) * 64 + ln) * 4 + k] = val;
    }
    __syncthreads();                        // wt ready (only barrier)

    // class owned by this lane after reduce-scatter = bit-reverse4(lane&15)
    const int cls = ((lane & 1) << 3) | (((lane >> 1) & 1) << 2)
                  | (((lane >> 2) & 1) << 1) | ((lane >> 3) & 1);
    const float bb = (cls < L_) ? bias[cls] : 0.0f;
    const int g = lane >> 4;                // epilogue group -> token-in-pass

    // ---- whole-wave constant slots (after barrier so block stays converged) ----
    if (basep >= cnt) {
        float cprob[L_];
        bias_softmax(bias, cprob);
        if (lane < 36)
            out[((size_t)row * S_ + basep) * L_ + lane] = cprob[lane % L_];
        return;
    }

    const float4* wt4 = reinterpret_cast<const float4*>(wt);

    // ---- per-lane partial dot products ----
    float acc[4][L_];
#pragma unroll
    for (int t = 0; t < 4; t++)
#pragma unroll
        for (int c = 0; c < L_; c++) acc[t][c] = 0.0f;

#pragma unroll
    for (int c = 0; c < L_; c++) {
#pragma unroll
        for (int j4 = 0; j4 < 3; j4++) {
            float4 wv = wt4[(c * 3 + j4) * 64 + lane];
#pragma unroll
            for (int t = 0; t < 4; t++) {
                acc[t][c] += x[t][j4 * 4 + 0] * wv.x + x[t][j4 * 4 + 1] * wv.y
                           + x[t][j4 * 4 + 2] * wv.z + x[t][j4 * 4 + 3] * wv.w;
            }
        }
    }

    // ---- reduce-scatter over 64 lanes, classes padded to 16 ----
    float logit[4];
#pragma unroll
    for (int t = 0; t < 4; t++) {
        float v[16];
#pragma unroll
        for (int c = 0; c < L_; c++) v[c] = acc[t][c];
#pragma unroll
        for (int c = L_; c < 16; c++) v[c] = 0.0f;

        {   // xor 1: keep low 8 if bit0==0 else high 8
            const bool b = (lane & 1);
#pragma unroll
            for (int i = 0; i < 8; i++) {
                float give = b ? v[i] : v[i + 8];
                float got  = __shfl_xor(give, 1);
                v[i] = (b ? v[i + 8] : v[i]) + got;
            }
        }
        {   // xor 2
            const bool b = ((lane >> 1) & 1);
#pragma unroll
            for (int i = 0; i < 4; i++) {
                float give = b ? v[i] : v[i + 4];
                float got  = __shfl_xor(give, 2);
                v[i] = (b ? v[i + 4] : v[i]) + got;
            }
        }
        {   // xor 4
            const bool b = ((lane >> 2) & 1);
#pragma unroll
            for (int i = 0; i < 2; i++) {
                float give = b ? v[i] : v[i + 2];
                float got  = __shfl_xor(give, 4);
                v[i] = (b ? v[i + 2] : v[i]) + got;
            }
        }
        {   // xor 8
            const bool b = ((lane >> 3) & 1);
            float give = b ? v[0] : v[1];
            float got  = __shfl_xor(give, 8);
            v[0] = (b ? v[1] : v[0]) + got;
        }
        v[0] += __shfl_xor(v[0], 16);
        v[0] += __shfl_xor(v[0], 32);
        logit[t] = v[0];                // full sum for class `cls`, all lanes
    }

    // ---- group-parallel softmax: group g handles token (basep+g) ----
    float lg = (g == 0) ? logit[0] : (g == 1) ? logit[1]
             : (g == 2) ? logit[2] : logit[3];
    lg += bb;
    float lx = (cls < L_) ? lg : -1e30f;
    float m = lx;
    m = fmaxf(m, __shfl_xor(m, 1));
    m = fmaxf(m, __shfl_xor(m, 2));
    m = fmaxf(m, __shfl_xor(m, 4));
    m = fmaxf(m, __shfl_xor(m, 8));
    float e = (cls < L_) ? __expf(lx - m) : 0.0f;
    float ssum = e;
    ssum += __shfl_xor(ssum, 1);
    ssum += __shfl_xor(ssum, 2);
    ssum += __shfl_xor(ssum, 4);
    ssum += __shfl_xor(ssum, 8);
    if (cls < L_)
        out[((size_t)row * S_ + basep + g) * L_ + cls] = e / ssum;
}

extern "C" void kernel_launch(void* const* d_in, const int* in_sizes, int n_in,
                              void* d_out, int out_size, void* d_ws, size_t ws_size,
                              hipStream_t stream) {
    const float* seq  = (const float*)d_in[0];   // [64,512,768] f32
    const int*   mask = (const int*)d_in[1];     // [64,512] int32
    const float* W    = (const float*)d_in[2];   // [768,9] f32
    const float* bias = (const float*)d_in[3];   // [9] f32
    float*       out  = (float*)d_out;           // [64,512,9] f32

    ner_kernel<<<B_ * BPR, 256, 0, stream>>>(seq, mask, W, bias, out);
}

// Round 5
// 147.834 us; speedup vs baseline: 1.0189x; 1.0189x over previous
//
#include <hip/hip_runtime.h>

#define B_ 64
#define S_ 512
#define H_ 768
#define L_ 9
#define TPB 16                       // tokens per block
#define BPR (S_ / TPB)               // 32 blocks per row

// ---------------------------------------------------------------------------
// Fused: per-row compaction + gathered GEMV (768->9) + softmax. f32 in/out.
// Block = 256 threads = 4 waves; wave w owns 4 output slots basep..basep+3.
//
// ROUND 5 — identical to round 4 (bench infra failed; kernel re-audited:
// bounds OK, barrier convergence OK, in-place reduce equivalent).
// Register-pressure + vmcnt-ordering pass:
//  * reduce-scatter runs IN PLACE on acc[t] (dead afterwards): -16 VGPR
//  * W staged via 27 regs (fully unrolled, coalesced), ISSUED BEFORE the 12
//    gather loads -> ds_writes wait vmcnt(12): gathers stay in flight across
//    the LDS write-out and the barrier
//  * peak live ~95 VGPR -> no spills at (256,4)
//  * compaction map is wave-private SALU: 8 mask loads + 8 ballots -> row
//    bitmap in SGPRs; slot->src = select pp-th set bit (scalar binary search)
//  * gather coalesced: lane i float4 at rowbase+(j*64+i)*16, j=0..2
// ---------------------------------------------------------------------------
__device__ __forceinline__ void bias_softmax(const float* __restrict__ bias,
                                             float* cprob) {
    float m = -3.4e38f;
#pragma unroll
    for (int c = 0; c < L_; c++) { cprob[c] = bias[c]; m = fmaxf(m, cprob[c]); }
    float s = 0.0f;
#pragma unroll
    for (int c = 0; c < L_; c++) { cprob[c] = __expf(cprob[c] - m); s += cprob[c]; }
    const float inv = 1.0f / s;
#pragma unroll
    for (int c = 0; c < L_; c++) cprob[c] *= inv;
}

__global__ __launch_bounds__(256, 4) void ner_kernel(const float* __restrict__ seq,
                                                     const int* __restrict__ mask,
                                                     const float* __restrict__ W,
                                                     const float* __restrict__ bias,
                                                     float* __restrict__ out) {
    __shared__ float wt[L_ * 3 * 64 * 4];   // [(cls*3+j)*64+lane] float4s, 27.6 KB

    const int tid  = threadIdx.x;
    const int lane = tid & 63;
    const int w    = __builtin_amdgcn_readfirstlane(tid >> 6);
    const int row  = blockIdx.x & 63;        // sub-major swizzle
    const int sub  = blockIdx.x >> 6;

    // ---- 1. per-wave full-row mask scan: 8 coalesced loads ----
    const int* mrow = mask + row * S_;
    int mv[8];
#pragma unroll
    for (int k = 0; k < 8; k++) mv[k] = mrow[64 * k + lane];

    // ---- 2. ballots -> row bitmap + prefix counts (all SGPR) ----
    unsigned long long bm[8];
    int csum[9];
    csum[0] = 0;
#pragma unroll
    for (int k = 0; k < 8; k++) {
        bm[k] = __ballot(mv[k] != 0);
        csum[k + 1] = csum[k] + __popcll(bm[k]);
    }
    const int cnt = csum[8];

    // ---- 3. whole-block early-out (uniform: same cnt/sub in all waves) ----
    if (sub * TPB >= cnt) {
        float cprob[L_];
        bias_softmax(bias, cprob);
        const int base = (row * S_ + sub * TPB) * L_;
        for (int idx = tid; idx < TPB * L_; idx += 256)
            out[base + idx] = cprob[idx % L_];
        return;
    }

    // ---- 4. W -> registers (27 coalesced dwords, issued BEFORE gathers) ----
    float wreg[27];
#pragma unroll
    for (int i = 0; i < 27; i++) wreg[i] = W[tid + 256 * i];

    const int basep = sub * TPB + w * 4;

    // ---- 5. slot->src scalar bit-select + issue 12 gather loads ----
    float x[4][12];
#pragma unroll
    for (int t = 0; t < 4; t++) {
        const int pp = basep + t;
        if (pp < cnt) {                     // wave-uniform (scalar branch)
            int k = 0;
#pragma unroll
            for (int j = 1; j < 8; j++) k += (pp >= csum[j]);
            int need = pp - csum[k];
            unsigned long long xm = bm[k];
            int src = 64 * k;
            int c32 = __popcll(xm & 0xFFFFFFFFull);
            if (need >= c32) { need -= c32; src += 32; xm >>= 32; }
            int c16 = __popcll(xm & 0xFFFFull);
            if (need >= c16) { need -= c16; src += 16; xm >>= 16; }
            int c8  = __popcll(xm & 0xFFull);
            if (need >= c8)  { need -= c8;  src += 8;  xm >>= 8; }
            int c4  = __popcll(xm & 0xFull);
            if (need >= c4)  { need -= c4;  src += 4;  xm >>= 4; }
            int c2  = __popcll(xm & 0x3ull);
            if (need >= c2)  { need -= c2;  src += 2;  xm >>= 2; }
            int c1  = (int)(xm & 1ull);
            if (need >= c1)  { src += 1; }

            const float4* p4 = reinterpret_cast<const float4*>(
                seq + ((size_t)row * S_ + src) * H_) + lane;
            float4 a0 = p4[0], a1 = p4[64], a2 = p4[128];
            x[t][0] = a0.x; x[t][1] = a0.y; x[t][2]  = a0.z; x[t][3]  = a0.w;
            x[t][4] = a1.x; x[t][5] = a1.y; x[t][6]  = a1.z; x[t][7]  = a1.w;
            x[t][8] = a2.x; x[t][9] = a2.y; x[t][10] = a2.z; x[t][11] = a2.w;
        } else {
#pragma unroll
            for (int kk = 0; kk < 12; kk++) x[t][kk] = 0.0f;  // -> softmax(bias)
        }
    }

    // ---- 6. wreg -> LDS transposed scatter (waits only W loads: vmcnt(12)) ----
    // idx = tid + 256*i; h = idx/9, c = idx%9; lane ln owns h = 256j+4ln+k:
    //   wt[((c*3+j)*64+ln)*4+k] = W[h*9+c]
#pragma unroll
    for (int i = 0; i < 27; i++) {
        const int idx = tid + 256 * i;
        const int h  = idx / 9;
        const int c  = idx - 9 * h;
        const int j  = h >> 8;
        const int r  = h & 255;
        const int ln = r >> 2;
        const int k  = r & 3;
        wt[((c * 3 + j) * 64 + ln) * 4 + k] = wreg[i];
    }
    __syncthreads();                        // wt ready (only barrier)

    // class owned by this lane after reduce-scatter = bit-reverse4(lane&15)
    const int cls = ((lane & 1) << 3) | (((lane >> 1) & 1) << 2)
                  | (((lane >> 2) & 1) << 1) | ((lane >> 3) & 1);
    const float bb = (cls < L_) ? bias[cls] : 0.0f;
    const int g = lane >> 4;                // epilogue group -> token-in-pass

    // ---- whole-wave constant slots (after barrier: block stays converged) ----
    if (basep >= cnt) {
        float cprob[L_];
        bias_softmax(bias, cprob);
        if (lane < 36)
            out[((size_t)row * S_ + basep) * L_ + lane] = cprob[lane % L_];
        return;
    }

    const float4* wt4 = reinterpret_cast<const float4*>(wt);

    // ---- 7. per-lane partial dot products ----
    float acc[4][L_];
#pragma unroll
    for (int t = 0; t < 4; t++)
#pragma unroll
        for (int c = 0; c < L_; c++) acc[t][c] = 0.0f;

#pragma unroll
    for (int c = 0; c < L_; c++) {
#pragma unroll
        for (int j4 = 0; j4 < 3; j4++) {
            float4 wv = wt4[(c * 3 + j4) * 64 + lane];
#pragma unroll
            for (int t = 0; t < 4; t++) {
                acc[t][c] += x[t][j4 * 4 + 0] * wv.x + x[t][j4 * 4 + 1] * wv.y
                           + x[t][j4 * 4 + 2] * wv.z + x[t][j4 * 4 + 3] * wv.w;
            }
        }
    }

    // ---- 8. reduce-scatter over 64 lanes, IN PLACE on acc[t] (9 padded->16) ----
    float logit[4];
#pragma unroll
    for (int t = 0; t < 4; t++) {
        float* a = acc[t];                  // acc[t] dead after this reduce
        {   // xor 1: logical v[0..15], v[8]=a[8], v[9..15]=0
            const bool b = (lane & 1);
#pragma unroll
            for (int i = 0; i < 8; i++) {
                float hi   = (i == 0) ? a[8] : 0.0f;
                float give = b ? a[i] : hi;
                float got  = __shfl_xor(give, 1);
                a[i] = (b ? hi : a[i]) + got;
            }
        }
        {   // xor 2
            const bool b = ((lane >> 1) & 1);
#pragma unroll
            for (int i = 0; i < 4; i++) {
                float give = b ? a[i] : a[i + 4];
                float got  = __shfl_xor(give, 2);
                a[i] = (b ? a[i + 4] : a[i]) + got;
            }
        }
        {   // xor 4
            const bool b = ((lane >> 2) & 1);
#pragma unroll
            for (int i = 0; i < 2; i++) {
                float give = b ? a[i] : a[i + 2];
                float got  = __shfl_xor(give, 4);
                a[i] = (b ? a[i + 2] : a[i]) + got;
            }
        }
        {   // xor 8
            const bool b = ((lane >> 3) & 1);
            float give = b ? a[0] : a[1];
            float got  = __shfl_xor(give, 8);
            a[0] = (b ? a[1] : a[0]) + got;
        }
        a[0] += __shfl_xor(a[0], 16);
        a[0] += __shfl_xor(a[0], 32);
        logit[t] = a[0];                    // full sum for class `cls`, all lanes
    }

    // ---- 9. group-parallel softmax: group g handles token (basep+g) ----
    float lg = (g == 0) ? logit[0] : (g == 1) ? logit[1]
             : (g == 2) ? logit[2] : logit[3];
    lg += bb;
    float lx = (cls < L_) ? lg : -1e30f;
    float m = lx;
    m = fmaxf(m, __shfl_xor(m, 1));
    m = fmaxf(m, __shfl_xor(m, 2));
    m = fmaxf(m, __shfl_xor(m, 4));
    m = fmaxf(m, __shfl_xor(m, 8));
    float e = (cls < L_) ? __expf(lx - m) : 0.0f;
    float ssum = e;
    ssum += __shfl_xor(ssum, 1);
    ssum += __shfl_xor(ssum, 2);
    ssum += __shfl_xor(ssum, 4);
    ssum += __shfl_xor(ssum, 8);
    if (cls < L_)
        out[((size_t)row * S_ + basep + g) * L_ + cls] = e / ssum;
}

extern "C" void kernel_launch(void* const* d_in, const int* in_sizes, int n_in,
                              void* d_out, int out_size, void* d_ws, size_t ws_size,
                              hipStream_t stream) {
    const float* seq  = (const float*)d_in[0];   // [64,512,768] f32
    const int*   mask = (const int*)d_in[1];     // [64,512] int32
    const float* W    = (const float*)d_in[2];   // [768,9] f32
    const float* bias = (const float*)d_in[3];   // [9] f32
    float*       out  = (float*)d_out;           // [64,512,9] f32

    ner_kernel<<<B_ * BPR, 256, 0, stream>>>(seq, mask, W, bias, out);
}